// Round 1
// baseline (1619.588 us; speedup 1.0000x reference)
//
#include <hip/hip_runtime.h>
#include <math.h>

// ---------- types / constants ----------
typedef __bf16 bf16x8 __attribute__((ext_vector_type(8)));
typedef short  s16x8  __attribute__((ext_vector_type(8)));
typedef float  f32x4  __attribute__((ext_vector_type(4)));
typedef float  fvec4  __attribute__((ext_vector_type(4)));

static constexpr int BSZ = 4, SEQ = 512, DM = 768;
static constexpr int DIN = 1536, NH = 48, HP = 32, NS = 64;
static constexpr int CDIM = 1664;          // DIN + 2*NS
static constexpr int PROJ_IN = 3248;
static constexpr int LDZX = 3328;          // PROJ_IN padded to x128
static constexpr int ROWS = BSZ * SEQ;     // 2048
static constexpr int EMBED = 1536;
static constexpr int NLAYERS = 12;

using gptr_t = const __attribute__((address_space(1))) void*;
using lptr_t = __attribute__((address_space(3))) void*;

__device__ __forceinline__ unsigned short f2bf(float f) {
  unsigned u = __builtin_bit_cast(unsigned, f);
  u += 0x7FFF + ((u >> 16) & 1);           // RNE
  return (unsigned short)(u >> 16);
}
__device__ __forceinline__ float sigm(float x) { return 1.f / (1.f + __expf(-x)); }

__device__ __forceinline__ void gll16(const void* g, void* l) {
  __builtin_amdgcn_global_load_lds((gptr_t)g, (lptr_t)l, 16, 0, 0);
}
__device__ __forceinline__ f32x4 mfma16(s16x8 a, s16x8 b, f32x4 c) {
  return __builtin_amdgcn_mfma_f32_16x16x32_bf16(
      __builtin_bit_cast(bf16x8, a), __builtin_bit_cast(bf16x8, b), c, 0, 0, 0);
}

__device__ __forceinline__ float block_sum_256(float v) {
#pragma unroll
  for (int o = 32; o; o >>= 1) v += __shfl_xor(v, o);
  __shared__ float red[4];
  if ((threadIdx.x & 63) == 0) red[threadIdx.x >> 6] = v;
  __syncthreads();
  return red[0] + red[1] + red[2] + red[3];
}

// ---------- embedding gather ----------
__global__ void embed_k(const int* __restrict__ tok, const float* __restrict__ eW,
                        float* __restrict__ x) {
  int bt = blockIdx.x;
  const float* src = eW + (size_t)tok[bt] * DM;
  float* dst = x + (size_t)bt * DM;
  for (int d = threadIdx.x; d < DM; d += 256) dst[d] = src[d];
}

// ---------- fp32 (K x N) -> bf16 (Npad x K) transpose-convert ----------
__global__ void transpose_cvt(const float* __restrict__ W, unsigned short* __restrict__ Wt,
                              int K, int N) {
  __shared__ float tile[32][33];
  int nb = blockIdx.x * 32, kb = blockIdx.y * 32;
  int tx = threadIdx.x, ty = threadIdx.y;
#pragma unroll
  for (int r = 0; r < 4; ++r) {
    int k = kb + ty + r * 8, n = nb + tx;
    tile[ty + r * 8][tx] = (n < N) ? W[(size_t)k * N + n] : 0.f;
  }
  __syncthreads();
#pragma unroll
  for (int r = 0; r < 4; ++r) {
    int n = nb + ty + r * 8, k = kb + tx;
    Wt[(size_t)n * K + k] = f2bf(tile[tx][ty + r * 8]);
  }
}

// ---------- rmsnorm (row=768), out fp32 or bf16 ----------
template <typename OUT>
__global__ void rmsnorm_k(const float* __restrict__ x, const float* __restrict__ w,
                          OUT* __restrict__ out) {
  int bt = blockIdx.x;
  const float* xr = x + (size_t)bt * DM;
  float v[3], ss = 0.f;
#pragma unroll
  for (int i = 0; i < 3; ++i) { v[i] = xr[threadIdx.x + i * 256]; ss += v[i] * v[i]; }
  float tot = block_sum_256(ss);
  float rs = rsqrtf(tot * (1.f / DM) + 1e-5f);
#pragma unroll
  for (int i = 0; i < 3; ++i) {
    int d = threadIdx.x + i * 256;
    float o = v[i] * rs * w[d];
    if constexpr (sizeof(OUT) == 4) out[(size_t)bt * DM + d] = o;
    else out[(size_t)bt * DM + d] = f2bf(o);
  }
}

// ---------- bf16 MFMA GEMM: A (MxK) @ Bt^T (Bt is NxK) -> C fp32 (M x ldc) ----------
template <bool ADD>
__global__ __launch_bounds__(256) void gemm_k(
    const unsigned short* __restrict__ A, const unsigned short* __restrict__ Bt,
    float* __restrict__ C, const float* __restrict__ Cin, int K, int ldc) {
  __shared__ unsigned short lA[128 * 64];
  __shared__ unsigned short lB[128 * 64];
  int tid = threadIdx.x, lane = tid & 63, wv = tid >> 6;
  int m0 = blockIdx.y * 128, n0 = blockIdx.x * 128;
  int wm = (wv >> 1) * 64, wn = (wv & 1) * 64;
  f32x4 acc[4][4] = {};
  for (int kt = 0; kt < K; kt += 64) {
    __syncthreads();
#pragma unroll
    for (int i = 0; i < 4; ++i) {
      int flat = i * 256 + tid;
      int rr = flat >> 3, cc = flat & 7;
      int cs = (cc ^ (rr & 7)) * 8;                     // pre-swizzled global source
      gll16(A + (size_t)(m0 + rr) * K + kt + cs, (char*)lA + flat * 16);
      gll16(Bt + (size_t)(n0 + rr) * K + kt + cs, (char*)lB + flat * 16);
    }
    asm volatile("s_waitcnt vmcnt(0)" ::: "memory");
    __syncthreads();
#pragma unroll
    for (int ks = 0; ks < 2; ++ks) {
      s16x8 a[4], b[4];
#pragma unroll
      for (int mi = 0; mi < 4; ++mi) {
        int row = wm + mi * 16 + (lane & 15);
        int ch = (ks * 4 + (lane >> 4)) ^ (row & 7);
        a[mi] = *(const s16x8*)((const char*)lA + row * 128 + ch * 16);
      }
#pragma unroll
      for (int nj = 0; nj < 4; ++nj) {
        int row = wn + nj * 16 + (lane & 15);
        int ch = (ks * 4 + (lane >> 4)) ^ (row & 7);
        b[nj] = *(const s16x8*)((const char*)lB + row * 128 + ch * 16);
      }
#pragma unroll
      for (int mi = 0; mi < 4; ++mi)
#pragma unroll
        for (int nj = 0; nj < 4; ++nj)
          acc[mi][nj] = mfma16(a[mi], b[nj], acc[mi][nj]);
    }
  }
#pragma unroll
  for (int mi = 0; mi < 4; ++mi) {
    int rbase = m0 + wm + mi * 16 + ((lane >> 4) << 2);
#pragma unroll
    for (int nj = 0; nj < 4; ++nj) {
      int col = n0 + wn + nj * 16 + (lane & 15);
#pragma unroll
      for (int rg = 0; rg < 4; ++rg) {
        size_t idx = (size_t)(rbase + rg) * ldc + col;
        float vv = acc[mi][nj][rg];
        if constexpr (ADD) vv += Cin[idx];
        C[idx] = vv;
      }
    }
  }
}

// ---------- causal depthwise conv(K=4) + silu, and dt=softplus ----------
__global__ void conv_dt_k(const float* __restrict__ zx, const float* __restrict__ cw,
                          const float* __restrict__ cb, const float* __restrict__ dbias,
                          float* __restrict__ convo, float* __restrict__ dtb) {
  int c = blockIdx.x * 256 + threadIdx.x;
  int bt = blockIdx.y;
  int t = bt & (SEQ - 1);
  if (c < CDIM) {
    float acc = cb[c];
    const float* w = cw + c * 4;
#pragma unroll
    for (int k = 0; k < 4; ++k) {
      int s = t - 3 + k;
      if (s >= 0) acc += zx[(size_t)(bt - 3 + k) * LDZX + DIN + c] * w[k];
    }
    convo[(size_t)bt * CDIM + c] = acc * sigm(acc);
  } else if (c < CDIM + NH) {
    int h = c - CDIM;
    float xv = zx[(size_t)bt * LDZX + DIN + CDIM + h] + dbias[h];
    dtb[bt * NH + h] = (xv > 15.f) ? xv : log1pf(__expf(xv));
  }
}

// ---------- per-(b,h) inclusive cumsum of dt*A over t ----------
__global__ void cumsum_k(const float* __restrict__ dtb, const float* __restrict__ alog,
                         float* __restrict__ ls) {
  __shared__ float buf[SEQ];
  int h = blockIdx.x, b = blockIdx.y, t = threadIdx.x;
  float Ah = -__expf(alog[h]);
  buf[t] = dtb[((size_t)b * SEQ + t) * NH + h] * Ah;
  __syncthreads();
  for (int off = 1; off < SEQ; off <<= 1) {
    float add = (t >= off) ? buf[t - off] : 0.f;
    float cur = buf[t];
    __syncthreads();
    buf[t] = cur + add;
    __syncthreads();
  }
  ls[((size_t)b * NH + h) * SEQ + t] = buf[t];
}

// ---------- SSM as tiled semiseparable matmul (flash-style) ----------
// y[t,p] = sum_{s<=t} exp(ls[t]-ls[s]) * (C_t . B_s) * (dt_s * x_s[p])  + D*x
__global__ __launch_bounds__(256) void scan_k(
    const float* __restrict__ conv, const float* __restrict__ dtb,
    const float* __restrict__ ls, const float* __restrict__ Dvec,
    float* __restrict__ y) {
  __shared__ unsigned short Cb[64 * 64], Bb[64 * 64], Pt[64 * 64], Dx[32 * 64];
  __shared__ float lsT[64], lsS[64];
  int tid = threadIdx.x, lane = tid & 63, wv = tid >> 6;
  int tb = blockIdx.x, h = blockIdx.y, b = blockIdx.z;
  int t0 = tb * 64;
  const float* lsrow = ls + ((size_t)b * NH + h) * SEQ;
  if (tid < 64) lsT[tid] = lsrow[t0 + tid];
  // stage C tile (rows t, cols n), XOR-swizzled
#pragma unroll
  for (int i = 0; i < 4; ++i) {
    int flat = i * 256 + tid;
    int rr = flat >> 4, cc = flat & 15;
    fvec4 v = *(const fvec4*)(conv + (size_t)(b * SEQ + t0 + rr) * CDIM + DIN + NS + cc * 4);
    unsigned long long pk =
        (unsigned long long)f2bf(v[0]) | ((unsigned long long)f2bf(v[1]) << 16) |
        ((unsigned long long)f2bf(v[2]) << 32) | ((unsigned long long)f2bf(v[3]) << 48);
    int off = (rr * 128 + cc * 8) ^ ((rr & 7) << 4);
    *(unsigned long long*)((char*)Cb + off) = pk;
  }
  __syncthreads();
  s16x8 aC[2];
#pragma unroll
  for (int ks = 0; ks < 2; ++ks) {
    int row = wv * 16 + (lane & 15);
    int ch = (ks * 4 + (lane >> 4)) ^ (row & 7);
    aC[ks] = *(const s16x8*)((const char*)Cb + row * 128 + ch * 16);
  }
  float lt[4];
#pragma unroll
  for (int rg = 0; rg < 4; ++rg) lt[rg] = lsT[wv * 16 + ((lane >> 4) << 2) + rg];
  f32x4 yacc[2] = {};

  for (int st = 0; st <= tb; ++st) {
    int s0 = st * 64;
    __syncthreads();                       // protect Bb/Dx from previous iter reads
    if (tid < 64) lsS[tid] = lsrow[s0 + tid];
#pragma unroll
    for (int i = 0; i < 4; ++i) {          // stage B tile
      int flat = i * 256 + tid;
      int rr = flat >> 4, cc = flat & 15;
      fvec4 v = *(const fvec4*)(conv + (size_t)(b * SEQ + s0 + rr) * CDIM + DIN + cc * 4);
      unsigned long long pk =
          (unsigned long long)f2bf(v[0]) | ((unsigned long long)f2bf(v[1]) << 16) |
          ((unsigned long long)f2bf(v[2]) << 32) | ((unsigned long long)f2bf(v[3]) << 48);
      int off = (rr * 128 + cc * 8) ^ ((rr & 7) << 4);
      *(unsigned long long*)((char*)Bb + off) = pk;
    }
#pragma unroll
    for (int i = 0; i < 2; ++i) {          // stage dtx transposed [p][s]
      int flat = i * 256 + tid;
      int ss = flat >> 3, pq = flat & 7;
      fvec4 v = *(const fvec4*)(conv + (size_t)(b * SEQ + s0 + ss) * CDIM + h * HP + pq * 4);
      float dv = dtb[((size_t)b * SEQ + s0 + ss) * NH + h];
#pragma unroll
      for (int j = 0; j < 4; ++j) {
        int p = pq * 4 + j;
        int off = (p * 128 + ss * 2) ^ ((p & 7) << 4);
        *(unsigned short*)((char*)Dx + off) = f2bf(v[j] * dv);
      }
    }
    __syncthreads();
    // G = C . B^T  (this wave's 16-row strip of t)
    f32x4 gf[4] = {};
#pragma unroll
    for (int sq = 0; sq < 4; ++sq) {
#pragma unroll
      for (int ks = 0; ks < 2; ++ks) {
        int row = sq * 16 + (lane & 15);
        int ch = (ks * 4 + (lane >> 4)) ^ (row & 7);
        s16x8 bB = *(const s16x8*)((const char*)Bb + row * 128 + ch * 16);
        gf[sq] = mfma16(aC[ks], bB, gf[sq]);
      }
    }
    // decay weighting + write P (bf16) to own rows
    int trb = wv * 16 + ((lane >> 4) << 2);
#pragma unroll
    for (int sq = 0; sq < 4; ++sq) {
      float lsv = lsS[sq * 16 + (lane & 15)];
      int sg = s0 + sq * 16 + (lane & 15);
#pragma unroll
      for (int rg = 0; rg < 4; ++rg) {
        int trow = trb + rg;
        int tg = t0 + trow;
        float wgt = (sg <= tg) ? __expf(lt[rg] - lsv) : 0.f;
        int off = (trow * 128 + (sq * 16 + (lane & 15)) * 2) ^ ((trow & 7) << 4);
        *(unsigned short*)((char*)Pt + off) = f2bf(gf[sq][rg] * wgt);
      }
    }
    // Y += P @ DTX  (wave-local rows of Pt; compiler orders LDS ops)
#pragma unroll
    for (int ks = 0; ks < 2; ++ks) {
      int row = wv * 16 + (lane & 15);
      int ch = (ks * 4 + (lane >> 4)) ^ (row & 7);
      s16x8 aP = *(const s16x8*)((const char*)Pt + row * 128 + ch * 16);
#pragma unroll
      for (int pq = 0; pq < 2; ++pq) {
        int prow = pq * 16 + (lane & 15);
        int pch = (ks * 4 + (lane >> 4)) ^ (prow & 7);
        s16x8 bD = *(const s16x8*)((const char*)Dx + prow * 128 + pch * 16);
        yacc[pq] = mfma16(aP, bD, yacc[pq]);
      }
    }
  }
  float Dh = Dvec[h];
#pragma unroll
  for (int pq = 0; pq < 2; ++pq) {
#pragma unroll
    for (int rg = 0; rg < 4; ++rg) {
      int trow = wv * 16 + ((lane >> 4) << 2) + rg;
      int tg = t0 + trow;
      int p = pq * 16 + (lane & 15);
      float xv = conv[(size_t)(b * SEQ + tg) * CDIM + h * HP + p];
      y[(size_t)(b * SEQ + tg) * DIN + h * HP + p] = yacc[pq][rg] + Dh * xv;
    }
  }
}

// ---------- gated rmsnorm: rmsnorm(y * silu(z)) -> bf16 ----------
__global__ void gated_rms_k(const float* __restrict__ y, const float* __restrict__ zx,
                            const float* __restrict__ w, unsigned short* __restrict__ out) {
  int bt = blockIdx.x;
  float v[6], ss = 0.f;
#pragma unroll
  for (int i = 0; i < 6; ++i) {
    int d = threadIdx.x + i * 256;
    float z = zx[(size_t)bt * LDZX + d];
    float g = y[(size_t)bt * DIN + d] * z * sigm(z);
    v[i] = g; ss += g * g;
  }
  float tot = block_sum_256(ss);
  float rs = rsqrtf(tot * (1.f / DIN) + 1e-5f);
#pragma unroll
  for (int i = 0; i < 6; ++i) {
    int d = threadIdx.x + i * 256;
    out[(size_t)bt * DIN + d] = f2bf(v[i] * rs * w[d]);
  }
}

// ---------- tail: pool, proj, l2-normalize ----------
__global__ void pool_k(const float* __restrict__ fn, float* __restrict__ pooled) {
  int d = blockIdx.x * 256 + threadIdx.x, b = blockIdx.y;
  float s = 0.f;
  for (int t = 0; t < SEQ; ++t) s += fn[(size_t)(b * SEQ + t) * DM + d];
  pooled[b * DM + d] = s * (1.f / SEQ);
}
__global__ void proj_k(const float* __restrict__ pooled, const float* __restrict__ pW,
                       const float* __restrict__ pb, float* __restrict__ ptmp) {
  int e = blockIdx.x * 256 + threadIdx.x, b = blockIdx.y;
  float s = pb[e];
  for (int d = 0; d < DM; ++d) s += pooled[b * DM + d] * pW[(size_t)d * EMBED + e];
  ptmp[b * EMBED + e] = s;
}
__global__ void l2_k(const float* __restrict__ ptmp, float* __restrict__ out) {
  int b = blockIdx.x;
  float v[6], ss = 0.f;
#pragma unroll
  for (int i = 0; i < 6; ++i) {
    v[i] = ptmp[(size_t)b * EMBED + threadIdx.x + i * 256];
    ss += v[i] * v[i];
  }
  float tot = block_sum_256(ss);
  float inv = 1.f / fmaxf(sqrtf(tot), 1e-12f);
#pragma unroll
  for (int i = 0; i < 6; ++i)
    out[(size_t)b * EMBED + threadIdx.x + i * 256] = v[i] * inv;
}

// ---------- launch ----------
extern "C" void kernel_launch(void* const* d_in, const int* in_sizes, int n_in,
                              void* d_out, int out_size, void* d_ws, size_t ws_size,
                              hipStream_t stream) {
  const int*   tok  = (const int*)d_in[0];
  const float* embW = (const float*)d_in[1];
  const float* lnW  = (const float*)d_in[2];
  const float* ipW  = (const float*)d_in[3];
  const float* cW   = (const float*)d_in[4];
  const float* cB   = (const float*)d_in[5];
  const float* dtB  = (const float*)d_in[6];
  const float* Alog = (const float*)d_in[7];
  const float* Dv   = (const float*)d_in[8];
  const float* nW   = (const float*)d_in[9];
  const float* opW  = (const float*)d_in[10];
  const float* fnW  = (const float*)d_in[11];
  const float* pW   = (const float*)d_in[12];
  const float* pb   = (const float*)d_in[13];
  float* out = (float*)d_out;

  char* wsp = (char*)d_ws;
  auto alloc = [&](size_t bytes) {
    char* p = wsp;
    wsp += (bytes + 255) & ~(size_t)255;
    return p;
  };
  float* x      = (float*)alloc((size_t)ROWS * DM * 4);
  float* zx     = (float*)alloc((size_t)ROWS * LDZX * 4);
  float* convb  = (float*)alloc((size_t)ROWS * CDIM * 4);
  float* yb     = (float*)alloc((size_t)ROWS * DIN * 4);
  float* dtb    = (float*)alloc((size_t)ROWS * NH * 4);
  float* lsb    = (float*)alloc((size_t)BSZ * NH * SEQ * 4);
  float* pooled = (float*)alloc((size_t)BSZ * DM * 4);
  float* ptmp   = (float*)alloc((size_t)BSZ * EMBED * 4);
  float* fn     = (float*)alloc((size_t)ROWS * DM * 4);
  unsigned short* h16  = (unsigned short*)alloc((size_t)ROWS * DM * 2);
  unsigned short* yg16 = (unsigned short*)alloc((size_t)ROWS * DIN * 2);
  unsigned short* wpt  = (unsigned short*)alloc((size_t)LDZX * DM * 2);
  unsigned short* wot  = (unsigned short*)alloc((size_t)DM * DIN * 2);

  embed_k<<<ROWS, 256, 0, stream>>>(tok, embW, x);

  for (int l = 0; l < NLAYERS; ++l) {
    transpose_cvt<<<dim3(LDZX / 32, DM / 32), dim3(32, 8), 0, stream>>>(
        ipW + (size_t)l * DM * PROJ_IN, wpt, DM, PROJ_IN);
    rmsnorm_k<unsigned short><<<ROWS, 256, 0, stream>>>(x, lnW + l * DM, h16);
    gemm_k<false><<<dim3(LDZX / 128, ROWS / 128), 256, 0, stream>>>(
        h16, wpt, zx, nullptr, DM, LDZX);
    conv_dt_k<<<dim3(7, ROWS), 256, 0, stream>>>(
        zx, cW + (size_t)l * CDIM * 4, cB + (size_t)l * CDIM, dtB + l * NH, convb, dtb);
    cumsum_k<<<dim3(NH, BSZ), SEQ, 0, stream>>>(dtb, Alog + l * NH, lsb);
    scan_k<<<dim3(SEQ / 64, NH, BSZ), 256, 0, stream>>>(convb, dtb, lsb, Dv + l * NH, yb);
    gated_rms_k<<<ROWS, 256, 0, stream>>>(yb, zx, nW + (size_t)l * DIN, yg16);
    transpose_cvt<<<dim3(DM / 32, DIN / 32), dim3(32, 8), 0, stream>>>(
        opW + (size_t)l * DIN * DM, wot, DIN, DM);
    gemm_k<true><<<dim3(DM / 128, ROWS / 128), 256, 0, stream>>>(
        yg16, wot, x, x, DIN, DM);
  }

  rmsnorm_k<float><<<ROWS, 256, 0, stream>>>(x, fnW, fn);
  pool_k<<<dim3(DM / 256, BSZ), 256, 0, stream>>>(fn, pooled);
  proj_k<<<dim3(EMBED / 256, BSZ), 256, 0, stream>>>(pooled, pW, pb, ptmp);
  l2_k<<<BSZ, 256, 0, stream>>>(ptmp, out);
}

// Round 2
// 1231.294 us; speedup vs baseline: 1.3154x; 1.3154x over previous
//
#include <hip/hip_runtime.h>
#include <math.h>

// ---------- types / constants ----------
typedef __bf16 bf16x8 __attribute__((ext_vector_type(8)));
typedef short  s16x8  __attribute__((ext_vector_type(8)));
typedef float  f32x4  __attribute__((ext_vector_type(4)));

static constexpr int BSZ = 4, SEQ = 512, DM = 768;
static constexpr int DIN = 1536, NH = 48, HP = 32, NS = 64;
static constexpr int CDIM = 1664;          // DIN + 2*NS
static constexpr int PROJ_IN = 3248;
static constexpr int LDZX = 3328;          // PROJ_IN padded to x128
static constexpr int ROWS = BSZ * SEQ;     // 2048
static constexpr int EMBED = 1536;
static constexpr int NLAYERS = 12;

using gptr_t = const __attribute__((address_space(1))) void*;
using lptr_t = __attribute__((address_space(3))) void*;

__device__ __forceinline__ unsigned short f2bf(float f) {
  unsigned u = __builtin_bit_cast(unsigned, f);
  u += 0x7FFF + ((u >> 16) & 1);           // RNE
  return (unsigned short)(u >> 16);
}
__device__ __forceinline__ float sigm(float x) { return 1.f / (1.f + __expf(-x)); }

__device__ __forceinline__ void gll16(const void* g, void* l) {
  __builtin_amdgcn_global_load_lds((gptr_t)g, (lptr_t)l, 16, 0, 0);
}
__device__ __forceinline__ f32x4 mfma16(s16x8 a, s16x8 b, f32x4 c) {
  return __builtin_amdgcn_mfma_f32_16x16x32_bf16(
      __builtin_bit_cast(bf16x8, a), __builtin_bit_cast(bf16x8, b), c, 0, 0, 0);
}

__device__ __forceinline__ float block_sum_256(float v) {
#pragma unroll
  for (int o = 32; o; o >>= 1) v += __shfl_xor(v, o);
  __shared__ float red[4];
  if ((threadIdx.x & 63) == 0) red[threadIdx.x >> 6] = v;
  __syncthreads();
  return red[0] + red[1] + red[2] + red[3];
}

// ---------- embedding gather ----------
__global__ void embed_k(const int* __restrict__ tok, const float* __restrict__ eW,
                        float* __restrict__ x) {
  int bt = blockIdx.x;
  const float* src = eW + (size_t)tok[bt] * DM;
  float* dst = x + (size_t)bt * DM;
  for (int d = threadIdx.x; d < DM; d += 256) dst[d] = src[d];
}

// ---------- fp32 (K x N) -> bf16 (Npad x K) transpose-convert, all layers ----------
__global__ void transpose_cvt(const float* __restrict__ W, unsigned short* __restrict__ Wt,
                              int K, int N, int Npad) {
  __shared__ float tile[32][33];
  int l = blockIdx.z;
  const float* Wl = W + (size_t)l * K * N;
  unsigned short* Wtl = Wt + (size_t)l * Npad * K;
  int nb = blockIdx.x * 32, kb = blockIdx.y * 32;
  int tx = threadIdx.x, ty = threadIdx.y;
#pragma unroll
  for (int r = 0; r < 4; ++r) {
    int k = kb + ty + r * 8, n = nb + tx;
    tile[ty + r * 8][tx] = (n < N) ? Wl[(size_t)k * N + n] : 0.f;
  }
  __syncthreads();
#pragma unroll
  for (int r = 0; r < 4; ++r) {
    int n = nb + ty + r * 8, k = kb + tx;
    Wtl[(size_t)n * K + k] = f2bf(tile[tx][ty + r * 8]);
  }
}

// ---------- rmsnorm (row=768), out fp32 or bf16 ----------
template <typename OUT>
__global__ void rmsnorm_k(const float* __restrict__ x, const float* __restrict__ w,
                          OUT* __restrict__ out) {
  int bt = blockIdx.x;
  const float* xr = x + (size_t)bt * DM;
  float v[3], ss = 0.f;
#pragma unroll
  for (int i = 0; i < 3; ++i) { v[i] = xr[threadIdx.x + i * 256]; ss += v[i] * v[i]; }
  float tot = block_sum_256(ss);
  float rs = rsqrtf(tot * (1.f / DM) + 1e-5f);
#pragma unroll
  for (int i = 0; i < 3; ++i) {
    int d = threadIdx.x + i * 256;
    float o = v[i] * rs * w[d];
    if constexpr (sizeof(OUT) == 4) out[(size_t)bt * DM + d] = o;
    else out[(size_t)bt * DM + d] = f2bf(o);
  }
}

// ---------- bf16 MFMA GEMM with LDS double-buffer + counted vmcnt ----------
template <int BM, int BN, bool ADD>
__global__ __launch_bounds__(256) void gemm_k(
    const unsigned short* __restrict__ A, const unsigned short* __restrict__ Bt,
    float* __restrict__ C, const float* __restrict__ Cin, int K, int ldc) {
  constexpr int AIT = BM / 32, BIT = BN / 32, NST = AIT + BIT;
  constexpr int FM = BM / 32, FN = BN / 32;
  __shared__ unsigned short lA[2][BM * 64], lB[2][BN * 64];
  int tid = threadIdx.x, lane = tid & 63, wv = tid >> 6;
  int m0 = blockIdx.y * BM, n0 = blockIdx.x * BN;
  int wm = (wv >> 1) * (BM / 2), wn = (wv & 1) * (BN / 2);
  int NK = K >> 6;
  auto stage = [&](int kt, int buf) {
#pragma unroll
    for (int i = 0; i < AIT; ++i) {
      int flat = i * 256 + tid, rr = flat >> 3, cc = flat & 7;
      gll16(A + (size_t)(m0 + rr) * K + kt + (cc ^ (rr & 7)) * 8, (char*)lA[buf] + flat * 16);
    }
#pragma unroll
    for (int i = 0; i < BIT; ++i) {
      int flat = i * 256 + tid, rr = flat >> 3, cc = flat & 7;
      gll16(Bt + (size_t)(n0 + rr) * K + kt + (cc ^ (rr & 7)) * 8, (char*)lB[buf] + flat * 16);
    }
  };
  f32x4 acc[FM][FN] = {};
  stage(0, 0);
  for (int i = 0; i < NK; ++i) {
    __syncthreads();
    if (i + 1 < NK) {
      stage((i + 1) << 6, (i + 1) & 1);
      asm volatile("s_waitcnt vmcnt(%0)" :: "i"(NST) : "memory");
    } else {
      asm volatile("s_waitcnt vmcnt(0)" ::: "memory");
    }
    __syncthreads();
    const unsigned short* cA = lA[i & 1];
    const unsigned short* cB = lB[i & 1];
#pragma unroll
    for (int ks = 0; ks < 2; ++ks) {
      s16x8 a[FM], b[FN];
#pragma unroll
      for (int mi = 0; mi < FM; ++mi) {
        int row = wm + mi * 16 + (lane & 15);
        int ch = (ks * 4 + (lane >> 4)) ^ (row & 7);
        a[mi] = *(const s16x8*)((const char*)cA + row * 128 + ch * 16);
      }
#pragma unroll
      for (int nj = 0; nj < FN; ++nj) {
        int row = wn + nj * 16 + (lane & 15);
        int ch = (ks * 4 + (lane >> 4)) ^ (row & 7);
        b[nj] = *(const s16x8*)((const char*)cB + row * 128 + ch * 16);
      }
#pragma unroll
      for (int mi = 0; mi < FM; ++mi)
#pragma unroll
        for (int nj = 0; nj < FN; ++nj)
          acc[mi][nj] = mfma16(a[mi], b[nj], acc[mi][nj]);
    }
  }
#pragma unroll
  for (int mi = 0; mi < FM; ++mi) {
    int rbase = m0 + wm + mi * 16 + ((lane >> 4) << 2);
#pragma unroll
    for (int nj = 0; nj < FN; ++nj) {
      int col = n0 + wn + nj * 16 + (lane & 15);
#pragma unroll
      for (int rg = 0; rg < 4; ++rg) {
        size_t idx = (size_t)(rbase + rg) * ldc + col;
        float vv = acc[mi][nj][rg];
        if constexpr (ADD) vv += Cin[idx];
        C[idx] = vv;
      }
    }
  }
}

// ---------- conv(K=4)+silu fused with dt/softplus; emits bf16 B,C,dtx^T + fp32 xs,dt ----------
__global__ __launch_bounds__(256) void conv_dt_k(
    const float* __restrict__ zx, const float* __restrict__ cw, const float* __restrict__ cb,
    const float* __restrict__ dbias, float* __restrict__ xs, unsigned short* __restrict__ dtxT,
    unsigned short* __restrict__ Bbf, unsigned short* __restrict__ Cbf,
    float* __restrict__ dtb) {
  __shared__ float stg[11][256];
  __shared__ float dtl[8][48];
  int tid = threadIdx.x;
  int chunk = blockIdx.x;                  // 0..6
  int bt0 = blockIdx.y * 8;
  int t0 = bt0 & (SEQ - 1);
  int cbase = chunk * 256;
#pragma unroll
  for (int i = 0; i < 11; ++i) {
    int s = t0 - 3 + i;
    stg[i][tid] = (s >= 0) ? zx[(size_t)(bt0 - 3 + i) * LDZX + DIN + cbase + tid] : 0.f;
  }
  if (chunk < 6) {
    for (int idx = tid; idx < 384; idx += 256) {
      int r = idx / 48, hh = idx - r * 48;
      float raw = zx[(size_t)(bt0 + r) * LDZX + DIN + CDIM + hh] + dbias[hh];
      dtl[r][hh] = (raw > 15.f) ? raw : log1pf(__expf(raw));
    }
  }
  __syncthreads();
  int c = cbase + tid;
  if (chunk < 6) {
    float w0 = cw[c * 4], w1 = cw[c * 4 + 1], w2 = cw[c * 4 + 2], w3 = cw[c * 4 + 3];
    float bias = cb[c];
    int hh = c >> 5, p = c & 31, b = bt0 >> 9;
    s16x8 pk;
#pragma unroll
    for (int r = 0; r < 8; ++r) {
      float a = bias + stg[r][tid] * w0 + stg[r + 1][tid] * w1 + stg[r + 2][tid] * w2 +
                stg[r + 3][tid] * w3;
      float sv = a * sigm(a);
      xs[(size_t)(bt0 + r) * DIN + c] = sv;
      pk[r] = (short)f2bf(sv * dtl[r][hh]);
    }
    *reinterpret_cast<s16x8*>(dtxT + ((((size_t)b * NH + hh) * HP + p) * SEQ + t0)) = pk;
  } else {
    if (tid < 128) {
      int cc = 1536 + tid;
      float w0 = cw[cc * 4], w1 = cw[cc * 4 + 1], w2 = cw[cc * 4 + 2], w3 = cw[cc * 4 + 3];
      float bias = cb[cc];
#pragma unroll
      for (int r = 0; r < 8; ++r) {
        float a = bias + stg[r][tid] * w0 + stg[r + 1][tid] * w1 + stg[r + 2][tid] * w2 +
                  stg[r + 3][tid] * w3;
        float sv = a * sigm(a);
        if (tid < 64) Bbf[(size_t)(bt0 + r) * NS + tid] = f2bf(sv);
        else          Cbf[(size_t)(bt0 + r) * NS + (tid - 64)] = f2bf(sv);
      }
    } else if (tid < 176) {
      int hh = tid - 128;
#pragma unroll
      for (int r = 0; r < 8; ++r) {
        float raw = stg[3 + r][128 + hh] + dbias[hh];
        dtb[(size_t)(bt0 + r) * NH + hh] = (raw > 15.f) ? raw : log1pf(__expf(raw));
      }
    }
  }
}

// ---------- per-(b,h) inclusive cumsum of dt*A over t ----------
__global__ void cumsum_k(const float* __restrict__ dtb, const float* __restrict__ alog,
                         float* __restrict__ ls) {
  __shared__ float buf[SEQ];
  int h = blockIdx.x, b = blockIdx.y, t = threadIdx.x;
  float Ah = -__expf(alog[h]);
  buf[t] = dtb[((size_t)b * SEQ + t) * NH + h] * Ah;
  __syncthreads();
  for (int off = 1; off < SEQ; off <<= 1) {
    float add = (t >= off) ? buf[t - off] : 0.f;
    float cur = buf[t];
    __syncthreads();
    buf[t] = cur + add;
    __syncthreads();
  }
  ls[((size_t)b * NH + h) * SEQ + t] = buf[t];
}

// ---------- SSM as tiled semiseparable matmul (flash-style, dbuf + gll16 staging) ----------
__global__ __launch_bounds__(256) void scan_k(
    const unsigned short* __restrict__ Bbf, const unsigned short* __restrict__ Cbf,
    const unsigned short* __restrict__ dtxT, const float* __restrict__ xs,
    const float* __restrict__ ls, const float* __restrict__ Dvec,
    float* __restrict__ y) {
  __shared__ unsigned short Cb[64 * 64], Bb[2][64 * 64], Dx[2][32 * 64], Pt[64 * 64];
  int tid = threadIdx.x, lane = tid & 63, wv = tid >> 6;
  int tb = blockIdx.x, h = blockIdx.y, b = blockIdx.z;
  int t0 = tb * 64;
  const float* lsrow = ls + ((size_t)b * NH + h) * SEQ;
  const unsigned short* dxrow = dtxT + ((size_t)b * NH + h) * HP * SEQ;

  // prologue staging: C (whole block) + B/Dx for st=0
#pragma unroll
  for (int i = 0; i < 2; ++i) {
    int flat = i * 256 + tid, rr = flat >> 3, cc = flat & 7;
    gll16(Cbf + (size_t)(b * SEQ + t0 + rr) * NS + (cc ^ (rr & 7)) * 8, (char*)Cb + flat * 16);
  }
#pragma unroll
  for (int i = 0; i < 2; ++i) {
    int flat = i * 256 + tid, rr = flat >> 3, cc = flat & 7;
    gll16(Bbf + (size_t)(b * SEQ + rr) * NS + (cc ^ (rr & 7)) * 8, (char*)Bb[0] + flat * 16);
  }
  { int rr = tid >> 3, cc = tid & 7;
    gll16(dxrow + (size_t)rr * SEQ + (cc ^ (rr & 7)) * 8, (char*)Dx[0] + tid * 16); }

  float REF = lsrow[t0];
  float lt[4], elt[4];
#pragma unroll
  for (int rg = 0; rg < 4; ++rg) {
    lt[rg] = lsrow[t0 + wv * 16 + ((lane >> 4) << 2) + rg];
    elt[rg] = __expf(lt[rg] - REF);
  }
  s16x8 aC[2];
  f32x4 yacc[2] = {};

  for (int st = 0; st <= tb; ++st) {
    int s0 = st * 64;
    __syncthreads();
    if (st < tb) {
      int s1 = s0 + 64;
#pragma unroll
      for (int i = 0; i < 2; ++i) {
        int flat = i * 256 + tid, rr = flat >> 3, cc = flat & 7;
        gll16(Bbf + (size_t)(b * SEQ + s1 + rr) * NS + (cc ^ (rr & 7)) * 8,
              (char*)Bb[(st + 1) & 1] + flat * 16);
      }
      { int rr = tid >> 3, cc = tid & 7;
        gll16(dxrow + (size_t)rr * SEQ + s1 + (cc ^ (rr & 7)) * 8,
              (char*)Dx[(st + 1) & 1] + tid * 16); }
      asm volatile("s_waitcnt vmcnt(3)" ::: "memory");
    } else {
      asm volatile("s_waitcnt vmcnt(0)" ::: "memory");
    }
    __syncthreads();
    const unsigned short* Bcur = Bb[st & 1];
    const unsigned short* Dcur = Dx[st & 1];
    if (st == 0) {
#pragma unroll
      for (int ks = 0; ks < 2; ++ks) {
        int row = wv * 16 + (lane & 15);
        int ch = (ks * 4 + (lane >> 4)) ^ (row & 7);
        aC[ks] = *(const s16x8*)((const char*)Cb + row * 128 + ch * 16);
      }
    }
    float lsv[4];
#pragma unroll
    for (int sq = 0; sq < 4; ++sq) lsv[sq] = lsrow[s0 + sq * 16 + (lane & 15)];
    // G = C . B^T (wave's 16-row strip)
    f32x4 gf[4] = {};
#pragma unroll
    for (int sq = 0; sq < 4; ++sq)
#pragma unroll
      for (int ks = 0; ks < 2; ++ks) {
        int row = sq * 16 + (lane & 15);
        int ch = (ks * 4 + (lane >> 4)) ^ (row & 7);
        s16x8 bB = *(const s16x8*)((const char*)Bcur + row * 128 + ch * 16);
        gf[sq] = mfma16(aC[ks], bB, gf[sq]);
      }
    // decay weighting + write P
    int trb = wv * 16 + ((lane >> 4) << 2);
    if (st < tb) {
      float es[4];
#pragma unroll
      for (int sq = 0; sq < 4; ++sq) es[sq] = __expf(REF - lsv[sq]);
#pragma unroll
      for (int sq = 0; sq < 4; ++sq) {
        int scol = sq * 16 + (lane & 15);
#pragma unroll
        for (int rg = 0; rg < 4; ++rg) {
          int trow = trb + rg;
          int off = (trow * 128 + scol * 2) ^ ((trow & 7) << 4);
          *(unsigned short*)((char*)Pt + off) = f2bf(gf[sq][rg] * (elt[rg] * es[sq]));
        }
      }
    } else {
#pragma unroll
      for (int sq = 0; sq < 4; ++sq) {
        int scol = sq * 16 + (lane & 15);
        int sg = s0 + scol;
#pragma unroll
        for (int rg = 0; rg < 4; ++rg) {
          int trow = trb + rg, tg = t0 + trow;
          float wgt = (sg <= tg) ? __expf(lt[rg] - lsv[sq]) : 0.f;
          int off = (trow * 128 + scol * 2) ^ ((trow & 7) << 4);
          *(unsigned short*)((char*)Pt + off) = f2bf(gf[sq][rg] * wgt);
        }
      }
    }
    // Y += P @ DxT (wave-local Pt rows)
#pragma unroll
    for (int ks = 0; ks < 2; ++ks) {
      int row = wv * 16 + (lane & 15);
      int ch = (ks * 4 + (lane >> 4)) ^ (row & 7);
      s16x8 aP = *(const s16x8*)((const char*)Pt + row * 128 + ch * 16);
#pragma unroll
      for (int pq = 0; pq < 2; ++pq) {
        int prow = pq * 16 + (lane & 15);
        int pch = (ks * 4 + (lane >> 4)) ^ (prow & 7);
        s16x8 bD = *(const s16x8*)((const char*)Dcur + prow * 128 + pch * 16);
        yacc[pq] = mfma16(aP, bD, yacc[pq]);
      }
    }
  }
  float Dh = Dvec[h];
#pragma unroll
  for (int pq = 0; pq < 2; ++pq) {
#pragma unroll
    for (int rg = 0; rg < 4; ++rg) {
      int trow = wv * 16 + ((lane >> 4) << 2) + rg;
      int tg = t0 + trow;
      int p = pq * 16 + (lane & 15);
      float xv = xs[(size_t)(b * SEQ + tg) * DIN + h * HP + p];
      y[(size_t)(b * SEQ + tg) * DIN + h * HP + p] = yacc[pq][rg] + Dh * xv;
    }
  }
}

// ---------- gated rmsnorm: rmsnorm(y * silu(z)) -> bf16 ----------
__global__ void gated_rms_k(const float* __restrict__ y, const float* __restrict__ zx,
                            const float* __restrict__ w, unsigned short* __restrict__ out) {
  int bt = blockIdx.x;
  float v[6], ss = 0.f;
#pragma unroll
  for (int i = 0; i < 6; ++i) {
    int d = threadIdx.x + i * 256;
    float z = zx[(size_t)bt * LDZX + d];
    float g = y[(size_t)bt * DIN + d] * z * sigm(z);
    v[i] = g; ss += g * g;
  }
  float tot = block_sum_256(ss);
  float rs = rsqrtf(tot * (1.f / DIN) + 1e-5f);
#pragma unroll
  for (int i = 0; i < 6; ++i) {
    int d = threadIdx.x + i * 256;
    out[(size_t)bt * DIN + d] = f2bf(v[i] * rs * w[d]);
  }
}

// ---------- tail: pool, proj, l2-normalize ----------
__global__ void pool_k(const float* __restrict__ fn, float* __restrict__ pooled) {
  int d = blockIdx.x * 256 + threadIdx.x, b = blockIdx.y;
  float s = 0.f;
  for (int t = 0; t < SEQ; ++t) s += fn[(size_t)(b * SEQ + t) * DM + d];
  pooled[b * DM + d] = s * (1.f / SEQ);
}
__global__ void proj_k(const float* __restrict__ pooled, const float* __restrict__ pW,
                       const float* __restrict__ pb, float* __restrict__ ptmp) {
  int e = blockIdx.x * 256 + threadIdx.x, b = blockIdx.y;
  float s = pb[e];
  for (int d = 0; d < DM; ++d) s += pooled[b * DM + d] * pW[(size_t)d * EMBED + e];
  ptmp[b * EMBED + e] = s;
}
__global__ void l2_k(const float* __restrict__ ptmp, float* __restrict__ out) {
  int b = blockIdx.x;
  float v[6], ss = 0.f;
#pragma unroll
  for (int i = 0; i < 6; ++i) {
    v[i] = ptmp[(size_t)b * EMBED + threadIdx.x + i * 256];
    ss += v[i] * v[i];
  }
  float tot = block_sum_256(ss);
  float inv = 1.f / fmaxf(sqrtf(tot), 1e-12f);
#pragma unroll
  for (int i = 0; i < 6; ++i)
    out[(size_t)b * EMBED + threadIdx.x + i * 256] = v[i] * inv;
}

// ---------- launch ----------
extern "C" void kernel_launch(void* const* d_in, const int* in_sizes, int n_in,
                              void* d_out, int out_size, void* d_ws, size_t ws_size,
                              hipStream_t stream) {
  const int*   tok  = (const int*)d_in[0];
  const float* embW = (const float*)d_in[1];
  const float* lnW  = (const float*)d_in[2];
  const float* ipW  = (const float*)d_in[3];
  const float* cW   = (const float*)d_in[4];
  const float* cB   = (const float*)d_in[5];
  const float* dtB  = (const float*)d_in[6];
  const float* Alog = (const float*)d_in[7];
  const float* Dv   = (const float*)d_in[8];
  const float* nW   = (const float*)d_in[9];
  const float* opW  = (const float*)d_in[10];
  const float* fnW  = (const float*)d_in[11];
  const float* pW   = (const float*)d_in[12];
  const float* pb   = (const float*)d_in[13];
  float* out = (float*)d_out;

  char* wsp = (char*)d_ws;
  auto alloc = [&](size_t bytes) {
    char* p = wsp;
    wsp += (bytes + 255) & ~(size_t)255;
    return p;
  };
  float* x      = (float*)alloc((size_t)ROWS * DM * 4);
  float* zx     = (float*)alloc((size_t)ROWS * LDZX * 4);
  float* xsb    = (float*)alloc((size_t)ROWS * DIN * 4);
  float* yb     = (float*)alloc((size_t)ROWS * DIN * 4);
  float* dtb    = (float*)alloc((size_t)ROWS * NH * 4);
  float* lsb    = (float*)alloc((size_t)BSZ * NH * SEQ * 4);
  float* pooled = (float*)alloc((size_t)BSZ * DM * 4);
  float* ptmp   = (float*)alloc((size_t)BSZ * EMBED * 4);
  float* fn     = (float*)alloc((size_t)ROWS * DM * 4);
  unsigned short* h16   = (unsigned short*)alloc((size_t)ROWS * DM * 2);
  unsigned short* yg16  = (unsigned short*)alloc((size_t)ROWS * DIN * 2);
  unsigned short* dtxT  = (unsigned short*)alloc((size_t)BSZ * NH * HP * SEQ * 2);
  unsigned short* Bbf   = (unsigned short*)alloc((size_t)ROWS * NS * 2);
  unsigned short* Cbf   = (unsigned short*)alloc((size_t)ROWS * NS * 2);
  unsigned short* wptA  = (unsigned short*)alloc((size_t)NLAYERS * LDZX * DM * 2);
  unsigned short* wotA  = (unsigned short*)alloc((size_t)NLAYERS * DM * DIN * 2);

  embed_k<<<ROWS, 256, 0, stream>>>(tok, embW, x);
  transpose_cvt<<<dim3(LDZX / 32, DM / 32, NLAYERS), dim3(32, 8), 0, stream>>>(
      ipW, wptA, DM, PROJ_IN, LDZX);
  transpose_cvt<<<dim3(DM / 32, DIN / 32, NLAYERS), dim3(32, 8), 0, stream>>>(
      opW, wotA, DIN, DM, DM);

  for (int l = 0; l < NLAYERS; ++l) {
    rmsnorm_k<unsigned short><<<ROWS, 256, 0, stream>>>(x, lnW + l * DM, h16);
    gemm_k<128, 128, false><<<dim3(LDZX / 128, ROWS / 128), 256, 0, stream>>>(
        h16, wptA + (size_t)l * LDZX * DM, zx, nullptr, DM, LDZX);
    conv_dt_k<<<dim3(7, ROWS / 8), 256, 0, stream>>>(
        zx, cW + (size_t)l * CDIM * 4, cB + (size_t)l * CDIM, dtB + l * NH,
        xsb, dtxT, Bbf, Cbf, dtb);
    cumsum_k<<<dim3(NH, BSZ), SEQ, 0, stream>>>(dtb, Alog + l * NH, lsb);
    scan_k<<<dim3(SEQ / 64, NH, BSZ), 256, 0, stream>>>(
        Bbf, Cbf, dtxT, xsb, lsb, Dv + l * NH, yb);
    gated_rms_k<<<ROWS, 256, 0, stream>>>(yb, zx, nW + (size_t)l * DIN, yg16);
    gemm_k<64, 64, true><<<dim3(DM / 64, ROWS / 64), 256, 0, stream>>>(
        yg16, wotA + (size_t)l * DM * DIN, x, x, DIN, DM);
  }

  rmsnorm_k<float><<<ROWS, 256, 0, stream>>>(x, fnW, fn);
  pool_k<<<dim3(DM / 256, BSZ), 256, 0, stream>>>(fn, pooled);
  proj_k<<<dim3(EMBED / 256, BSZ), 256, 0, stream>>>(pooled, pW, pb, ptmp);
  l2_k<<<BSZ, 256, 0, stream>>>(ptmp, out);
}

// Round 3
// 1064.664 us; speedup vs baseline: 1.5212x; 1.1565x over previous
//
#include <hip/hip_runtime.h>
#include <math.h>

// ---------- types / constants ----------
typedef __bf16 bf16x8 __attribute__((ext_vector_type(8)));
typedef short  s16x8  __attribute__((ext_vector_type(8)));
typedef float  f32x4  __attribute__((ext_vector_type(4)));

static constexpr int BSZ = 4, SEQ = 512, DM = 768;
static constexpr int DIN = 1536, NH = 48, HP = 32, NS = 64;
static constexpr int CDIM = 1664;          // DIN + 2*NS
static constexpr int PROJ_IN = 3248;
static constexpr int LDZX = 3328;          // PROJ_IN padded to x128
static constexpr int ROWS = BSZ * SEQ;     // 2048
static constexpr int EMBED = 1536;
static constexpr int NLAYERS = 12;

using gptr_t = const __attribute__((address_space(1))) void*;
using lptr_t = __attribute__((address_space(3))) void*;

__device__ __forceinline__ unsigned short f2bf(float f) {
  unsigned u = __builtin_bit_cast(unsigned, f);
  u += 0x7FFF + ((u >> 16) & 1);           // RNE
  return (unsigned short)(u >> 16);
}
__device__ __forceinline__ float bf2f(unsigned short u) {
  unsigned v = (unsigned)u << 16;
  return __builtin_bit_cast(float, v);
}
__device__ __forceinline__ float sigm(float x) { return 1.f / (1.f + __expf(-x)); }
__device__ __forceinline__ float sp(float x) { return (x > 15.f) ? x : log1pf(__expf(x)); }

__device__ __forceinline__ void gll16(const void* g, void* l) {
  __builtin_amdgcn_global_load_lds((gptr_t)g, (lptr_t)l, 16, 0, 0);
}
__device__ __forceinline__ f32x4 mfma16(s16x8 a, s16x8 b, f32x4 c) {
  return __builtin_amdgcn_mfma_f32_16x16x32_bf16(
      __builtin_bit_cast(bf16x8, a), __builtin_bit_cast(bf16x8, b), c, 0, 0, 0);
}

template <int NW>
__device__ __forceinline__ float block_sum(float v) {
#pragma unroll
  for (int o = 32; o; o >>= 1) v += __shfl_xor(v, o);
  __shared__ float red[NW];
  if ((threadIdx.x & 63) == 0) red[threadIdx.x >> 6] = v;
  __syncthreads();
  float s = red[0];
#pragma unroll
  for (int i = 1; i < NW; ++i) s += red[i];
  return s;
}

// ---------- embedding gather (192 thr, float4) ----------
__global__ void embed_k(const int* __restrict__ tok, const float* __restrict__ eW,
                        float* __restrict__ x) {
  int bt = blockIdx.x;
  const float4* src = (const float4*)(eW + (size_t)tok[bt] * DM);
  float4* dst = (float4*)(x + (size_t)bt * DM);
  dst[threadIdx.x] = src[threadIdx.x];
}

// ---------- fp32 (K x N) -> bf16 (Npad x K) transpose-convert, all layers ----------
__global__ void transpose_cvt(const float* __restrict__ W, unsigned short* __restrict__ Wt,
                              int K, int N, int Npad) {
  __shared__ float tile[32][33];
  int l = blockIdx.z;
  const float* Wl = W + (size_t)l * K * N;
  unsigned short* Wtl = Wt + (size_t)l * Npad * K;
  int nb = blockIdx.x * 32, kb = blockIdx.y * 32;
  int tx = threadIdx.x, ty = threadIdx.y;
#pragma unroll
  for (int r = 0; r < 4; ++r) {
    int k = kb + ty + r * 8, n = nb + tx;
    tile[ty + r * 8][tx] = (n < N) ? Wl[(size_t)k * N + n] : 0.f;
  }
  __syncthreads();
#pragma unroll
  for (int r = 0; r < 4; ++r) {
    int n = nb + ty + r * 8, k = kb + tx;
    Wtl[(size_t)n * K + k] = f2bf(tile[tx][ty + r * 8]);
  }
}

// ---------- rmsnorm (row=768), 192 thr float4 in; out fp32 or bf16 ----------
template <typename OUT>
__global__ void rmsnorm_k(const float* __restrict__ x, const float* __restrict__ w,
                          OUT* __restrict__ out) {
  int bt = blockIdx.x, tid = threadIdx.x;
  float4 v = ((const float4*)(x + (size_t)bt * DM))[tid];
  float4 wv = ((const float4*)w)[tid];
  float ss = v.x * v.x + v.y * v.y + v.z * v.z + v.w * v.w;
  float tot = block_sum<3>(ss);
  float rs = rsqrtf(tot * (1.f / DM) + 1e-5f);
  float o0 = v.x * rs * wv.x, o1 = v.y * rs * wv.y, o2 = v.z * rs * wv.z, o3 = v.w * rs * wv.w;
  if constexpr (sizeof(OUT) == 4) {
    float4 o = {o0, o1, o2, o3};
    ((float4*)(out + (size_t)bt * DM))[tid] = o;
  } else {
    unsigned long long pk =
        (unsigned long long)f2bf(o0) | ((unsigned long long)f2bf(o1) << 16) |
        ((unsigned long long)f2bf(o2) << 32) | ((unsigned long long)f2bf(o3) << 48);
    *(unsigned long long*)((unsigned short*)out + (size_t)bt * DM + tid * 4) = pk;
  }
}

// ---------- bf16 MFMA GEMM, dbuf LDS + raw barriers + counted vmcnt ----------
// MODE 0: split-write zxbcdt -> (zb bf16 | xbc fp32 ld1664 | dtraw fp32 48)
// MODE 1: x += A@Bt^T (fp32, ldc 768)
template <int BM, int BN, int MODE>
__global__ __launch_bounds__(256) void gemm_k(
    const unsigned short* __restrict__ A, const unsigned short* __restrict__ Bt,
    int K, void* __restrict__ O0, void* __restrict__ O1, void* __restrict__ O2) {
  constexpr int AIT = BM / 32, BIT = BN / 32, NST = AIT + BIT;
  constexpr int FM = BM / 32, FN = BN / 32;
  __shared__ unsigned short lA[2][BM * 64], lB[2][BN * 64];
  int tid = threadIdx.x, lane = tid & 63, wv = tid >> 6;
  // bijective XCD swizzle (grid % 8 == 0 for both GEMMs)
  int flat = blockIdx.y * gridDim.x + blockIdx.x;
  int q8 = (gridDim.x * gridDim.y) >> 3;
  int nf = (flat & 7) * q8 + (flat >> 3);
  int bx = nf % gridDim.x, by = nf / gridDim.x;
  int m0 = by * BM, n0 = bx * BN;
  int wm = (wv >> 1) * (BM / 2), wn = (wv & 1) * (BN / 2);
  int NK = K >> 6;
  auto stage = [&](int kt, int buf) {
#pragma unroll
    for (int i = 0; i < AIT; ++i) {
      int flt = i * 256 + tid, rr = flt >> 3, cc = flt & 7;
      gll16(A + (size_t)(m0 + rr) * K + kt + (cc ^ (rr & 7)) * 8, (char*)lA[buf] + flt * 16);
    }
#pragma unroll
    for (int i = 0; i < BIT; ++i) {
      int flt = i * 256 + tid, rr = flt >> 3, cc = flt & 7;
      gll16(Bt + (size_t)(n0 + rr) * K + kt + (cc ^ (rr & 7)) * 8, (char*)lB[buf] + flt * 16);
    }
  };
  f32x4 acc[FM][FN] = {};
  stage(0, 0);
  for (int i = 0; i < NK; ++i) {
    if (i + 1 < NK) {
      stage((i + 1) << 6, (i + 1) & 1);
      asm volatile("s_waitcnt vmcnt(%0)" :: "i"(NST) : "memory");
    } else {
      asm volatile("s_waitcnt vmcnt(0)" ::: "memory");
    }
    __builtin_amdgcn_s_barrier();
    __builtin_amdgcn_sched_barrier(0);
    const unsigned short* cA = lA[i & 1];
    const unsigned short* cB = lB[i & 1];
#pragma unroll
    for (int ks = 0; ks < 2; ++ks) {
      s16x8 a[FM], b[FN];
#pragma unroll
      for (int mi = 0; mi < FM; ++mi) {
        int row = wm + mi * 16 + (lane & 15);
        int ch = (ks * 4 + (lane >> 4)) ^ (row & 7);
        a[mi] = *(const s16x8*)((const char*)cA + row * 128 + ch * 16);
      }
#pragma unroll
      for (int nj = 0; nj < FN; ++nj) {
        int row = wn + nj * 16 + (lane & 15);
        int ch = (ks * 4 + (lane >> 4)) ^ (row & 7);
        b[nj] = *(const s16x8*)((const char*)cB + row * 128 + ch * 16);
      }
#pragma unroll
      for (int mi = 0; mi < FM; ++mi)
#pragma unroll
        for (int nj = 0; nj < FN; ++nj)
          acc[mi][nj] = mfma16(a[mi], b[nj], acc[mi][nj]);
    }
    __builtin_amdgcn_s_barrier();
  }
#pragma unroll
  for (int mi = 0; mi < FM; ++mi) {
    int rbase = m0 + wm + mi * 16 + ((lane >> 4) << 2);
#pragma unroll
    for (int nj = 0; nj < FN; ++nj) {
      int col = n0 + wn + nj * 16 + (lane & 15);
#pragma unroll
      for (int rg = 0; rg < 4; ++rg) {
        int row = rbase + rg;
        float vv = acc[mi][nj][rg];
        if constexpr (MODE == 0) {
          if (n0 < DIN) {
            ((unsigned short*)O0)[(size_t)row * DIN + col] = f2bf(vv);
          } else if (n0 < DIN + CDIM) {
            ((float*)O1)[(size_t)row * CDIM + (col - DIN)] = vv;
          } else {
            int c2 = col - (DIN + CDIM);
            if (c2 < NH) ((float*)O2)[(size_t)row * NH + c2] = vv;
          }
        } else {
          size_t idx = (size_t)row * DM + col;
          ((float*)O0)[idx] = vv + ((const float*)O1)[idx];
        }
      }
    }
  }
}

// ---------- conv(K=4)+silu; emits bf16 xs, dtx^T, B, C ----------
__global__ __launch_bounds__(256) void conv_dt_k(
    const float* __restrict__ xbc, const float* __restrict__ cw, const float* __restrict__ cb,
    const float* __restrict__ dtraw, const float* __restrict__ dbias,
    unsigned short* __restrict__ xs16, unsigned short* __restrict__ dtxT,
    unsigned short* __restrict__ Bbf, unsigned short* __restrict__ Cbf) {
  __shared__ float stg[11][256];
  __shared__ float dtl[8][48];
  int tid = threadIdx.x;
  int chunk = blockIdx.x;                  // 0..6
  int bt0 = blockIdx.y * 8;
  int t0 = bt0 & (SEQ - 1);
  int cbase = chunk * 256;
#pragma unroll
  for (int i = 0; i < 11; ++i) {
    int s = t0 - 3 + i, col = cbase + tid;
    stg[i][tid] = (s >= 0 && col < CDIM) ? xbc[(size_t)(bt0 - 3 + i) * CDIM + col] : 0.f;
  }
  if (chunk < 6) {
    for (int idx = tid; idx < 384; idx += 256) {
      int r = idx / 48, hh = idx - r * 48;
      dtl[r][hh] = sp(dtraw[(size_t)(bt0 + r) * NH + hh] + dbias[hh]);
    }
  }
  __syncthreads();
  int c = cbase + tid;
  if (chunk < 6) {
    float w0 = cw[c * 4], w1 = cw[c * 4 + 1], w2 = cw[c * 4 + 2], w3 = cw[c * 4 + 3];
    float bias = cb[c];
    int hh = c >> 5, p = c & 31, b = bt0 >> 9;
    s16x8 pk;
#pragma unroll
    for (int r = 0; r < 8; ++r) {
      float a = bias + stg[r][tid] * w0 + stg[r + 1][tid] * w1 + stg[r + 2][tid] * w2 +
                stg[r + 3][tid] * w3;
      float sv = a * sigm(a);
      xs16[(size_t)(bt0 + r) * DIN + c] = f2bf(sv);
      pk[r] = (short)f2bf(sv * dtl[r][hh]);
    }
    *reinterpret_cast<s16x8*>(dtxT + ((((size_t)b * NH + hh) * HP + p) * SEQ + t0)) = pk;
  } else if (tid < 128) {
    int cc = DIN + tid;
    float w0 = cw[cc * 4], w1 = cw[cc * 4 + 1], w2 = cw[cc * 4 + 2], w3 = cw[cc * 4 + 3];
    float bias = cb[cc];
#pragma unroll
    for (int r = 0; r < 8; ++r) {
      float a = bias + stg[r][tid] * w0 + stg[r + 1][tid] * w1 + stg[r + 2][tid] * w2 +
                stg[r + 3][tid] * w3;
      float sv = a * sigm(a);
      if (tid < 64) Bbf[(size_t)(bt0 + r) * NS + tid] = f2bf(sv);
      else          Cbf[(size_t)(bt0 + r) * NS + (tid - 64)] = f2bf(sv);
    }
  }
}

// ---------- SSM: fused softplus+cumsum, decay-truncated tiled semiseparable matmul ----------
__global__ __launch_bounds__(256) void scan_k(
    const unsigned short* __restrict__ Bbf, const unsigned short* __restrict__ Cbf,
    const unsigned short* __restrict__ dtxT, const unsigned short* __restrict__ xs16,
    const float* __restrict__ dtraw, const float* __restrict__ dbias,
    const float* __restrict__ alog, const float* __restrict__ Dvec,
    unsigned short* __restrict__ y16) {
  __shared__ unsigned short CbPt[64 * 64];   // C tile, then reused as P tile
  __shared__ unsigned short Bb[2][64 * 64], Dx[2][32 * 64];
  __shared__ float lsb[SEQ];
  __shared__ float pair[256];
  __shared__ int sfirst;
  int tid = threadIdx.x, lane = tid & 63, wv = tid >> 6;
  int tb = blockIdx.x, h = blockIdx.y, b = blockIdx.z;
  int t0 = tb * 64;
  const unsigned short* dxrow = dtxT + ((size_t)b * NH + h) * HP * SEQ;

  // issue C staging early
#pragma unroll
  for (int i = 0; i < 2; ++i) {
    int flt = i * 256 + tid, rr = flt >> 3, cc = flt & 7;
    gll16(Cbf + (size_t)(b * SEQ + t0 + rr) * NS + (cc ^ (rr & 7)) * 8, (char*)CbPt + flt * 16);
  }
  // fused dt=softplus, ls=cumsum(dt*A)
  float bias = dbias[h];
  float Ah = -__expf(alog[h]);
  int t2 = tid * 2;
  float d0 = sp(dtraw[(size_t)(b * SEQ + t2) * NH + h] + bias) * Ah;
  float d1 = sp(dtraw[(size_t)(b * SEQ + t2 + 1) * NH + h] + bias) * Ah;
  pair[tid] = d0 + d1;
  __syncthreads();
  for (int off = 1; off < 256; off <<= 1) {
    float add = (tid >= off) ? pair[tid - off] : 0.f;
    float cur = pair[tid];
    __syncthreads();
    pair[tid] = cur + add;
    __syncthreads();
  }
  float excl = tid ? pair[tid - 1] : 0.f;
  lsb[t2] = excl + d0;
  lsb[t2 + 1] = excl + d0 + d1;
  if (tid == 0) sfirst = tb;
  __syncthreads();
  float REF = lsb[t0];
  // earliest s-tile with non-negligible decay (monotone predicate)
  if (tid < tb && (REF - lsb[tid * 64 + 63] >= -18.f)) atomicMin(&sfirst, tid);
  __syncthreads();
  int st0 = sfirst;

  // stage B/Dx for st0
#pragma unroll
  for (int i = 0; i < 2; ++i) {
    int flt = i * 256 + tid, rr = flt >> 3, cc = flt & 7;
    gll16(Bbf + (size_t)(b * SEQ + st0 * 64 + rr) * NS + (cc ^ (rr & 7)) * 8,
          (char*)Bb[st0 & 1] + flt * 16);
  }
  { int rr = tid >> 3, cc = tid & 7;
    gll16(dxrow + (size_t)rr * SEQ + st0 * 64 + (cc ^ (rr & 7)) * 8,
          (char*)Dx[st0 & 1] + tid * 16); }

  float lt[4], elt[4];
  int trb = wv * 16 + ((lane >> 4) << 2);
#pragma unroll
  for (int rg = 0; rg < 4; ++rg) {
    lt[rg] = lsb[t0 + trb + rg];
    elt[rg] = __expf(lt[rg] - REF);
  }
  s16x8 aC[2];
  f32x4 yacc[2] = {};

  for (int st = st0; st <= tb; ++st) {
    int s0 = st * 64;
    if (st < tb) {
      int s1 = s0 + 64;
#pragma unroll
      for (int i = 0; i < 2; ++i) {
        int flt = i * 256 + tid, rr = flt >> 3, cc = flt & 7;
        gll16(Bbf + (size_t)(b * SEQ + s1 + rr) * NS + (cc ^ (rr & 7)) * 8,
              (char*)Bb[(st + 1) & 1] + flt * 16);
      }
      { int rr = tid >> 3, cc = tid & 7;
        gll16(dxrow + (size_t)rr * SEQ + s1 + (cc ^ (rr & 7)) * 8,
              (char*)Dx[(st + 1) & 1] + tid * 16); }
      asm volatile("s_waitcnt vmcnt(3)" ::: "memory");
    } else {
      asm volatile("s_waitcnt vmcnt(0)" ::: "memory");
    }
    __builtin_amdgcn_s_barrier();
    __builtin_amdgcn_sched_barrier(0);
    const unsigned short* Bcur = Bb[st & 1];
    const unsigned short* Dcur = Dx[st & 1];
    if (st == st0) {   // C fragments (CbPt later reused as Pt; wave-local rows, safe)
#pragma unroll
      for (int ks = 0; ks < 2; ++ks) {
        int row = wv * 16 + (lane & 15);
        int ch = (ks * 4 + (lane >> 4)) ^ (row & 7);
        aC[ks] = *(const s16x8*)((const char*)CbPt + row * 128 + ch * 16);
      }
    }
    float lsv[4];
#pragma unroll
    for (int sq = 0; sq < 4; ++sq) lsv[sq] = lsb[s0 + sq * 16 + (lane & 15)];
    // G = C . B^T (wave's 16-row t-strip)
    f32x4 gf[4] = {};
#pragma unroll
    for (int sq = 0; sq < 4; ++sq)
#pragma unroll
      for (int ks = 0; ks < 2; ++ks) {
        int row = sq * 16 + (lane & 15);
        int ch = (ks * 4 + (lane >> 4)) ^ (row & 7);
        s16x8 bB = *(const s16x8*)((const char*)Bcur + row * 128 + ch * 16);
        gf[sq] = mfma16(aC[ks], bB, gf[sq]);
      }
    // decay weighting + write P (into CbPt)
    if (st < tb) {
      float es[4];
#pragma unroll
      for (int sq = 0; sq < 4; ++sq) es[sq] = __expf(REF - lsv[sq]);
#pragma unroll
      for (int sq = 0; sq < 4; ++sq) {
        int scol = sq * 16 + (lane & 15);
#pragma unroll
        for (int rg = 0; rg < 4; ++rg) {
          int trow = trb + rg;
          int off = (trow * 128 + scol * 2) ^ ((trow & 7) << 4);
          *(unsigned short*)((char*)CbPt + off) = f2bf(gf[sq][rg] * (elt[rg] * es[sq]));
        }
      }
    } else {
#pragma unroll
      for (int sq = 0; sq < 4; ++sq) {
        int scol = sq * 16 + (lane & 15);
        int sg = s0 + scol;
#pragma unroll
        for (int rg = 0; rg < 4; ++rg) {
          int trow = trb + rg, tg = t0 + trow;
          float wgt = (sg <= tg) ? __expf(lt[rg] - lsv[sq]) : 0.f;
          int off = (trow * 128 + scol * 2) ^ ((trow & 7) << 4);
          *(unsigned short*)((char*)CbPt + off) = f2bf(gf[sq][rg] * wgt);
        }
      }
    }
    // Y += P @ DxT (wave-local Pt rows)
#pragma unroll
    for (int ks = 0; ks < 2; ++ks) {
      int row = wv * 16 + (lane & 15);
      int ch = (ks * 4 + (lane >> 4)) ^ (row & 7);
      s16x8 aP = *(const s16x8*)((const char*)CbPt + row * 128 + ch * 16);
#pragma unroll
      for (int pq = 0; pq < 2; ++pq) {
        int prow = pq * 16 + (lane & 15);
        int pch = (ks * 4 + (lane >> 4)) ^ (prow & 7);
        s16x8 bD = *(const s16x8*)((const char*)Dcur + prow * 128 + pch * 16);
        yacc[pq] = mfma16(aP, bD, yacc[pq]);
      }
    }
    __builtin_amdgcn_s_barrier();
  }
  float Dh = Dvec[h];
#pragma unroll
  for (int pq = 0; pq < 2; ++pq) {
#pragma unroll
    for (int rg = 0; rg < 4; ++rg) {
      int trow = trb + rg;
      int tg = t0 + trow;
      int p = pq * 16 + (lane & 15);
      float xv = bf2f(xs16[(size_t)(b * SEQ + tg) * DIN + h * HP + p]);
      y16[(size_t)(b * SEQ + tg) * DIN + h * HP + p] = f2bf(yacc[pq][rg] + Dh * xv);
    }
  }
}

// ---------- gated rmsnorm: rmsnorm(y * silu(z)) -> bf16 (192 thr x 8) ----------
__global__ void gated_rms_k(const unsigned short* __restrict__ y16,
                            const unsigned short* __restrict__ zb,
                            const float* __restrict__ w, unsigned short* __restrict__ out) {
  int bt = blockIdx.x, tid = threadIdx.x;
  size_t base = (size_t)bt * DIN + tid * 8;
  s16x8 yv = *(const s16x8*)(y16 + base);
  s16x8 zv = *(const s16x8*)(zb + base);
  float g[8], ss = 0.f;
#pragma unroll
  for (int j = 0; j < 8; ++j) {
    float yf = bf2f((unsigned short)yv[j]), zf = bf2f((unsigned short)zv[j]);
    float gg = yf * zf * sigm(zf);
    g[j] = gg; ss += gg * gg;
  }
  float tot = block_sum<3>(ss);
  float rs = rsqrtf(tot * (1.f / DIN) + 1e-5f);
  s16x8 ov;
#pragma unroll
  for (int j = 0; j < 8; ++j) ov[j] = (short)f2bf(g[j] * rs * w[tid * 8 + j]);
  *(s16x8*)(out + base) = ov;
}

// ---------- tail: pool, proj, l2-normalize ----------
__global__ void pool_k(const float* __restrict__ fn, float* __restrict__ pooled) {
  int d = blockIdx.x * 256 + threadIdx.x, b = blockIdx.y;
  float s = 0.f;
  for (int t = 0; t < SEQ; ++t) s += fn[(size_t)(b * SEQ + t) * DM + d];
  pooled[b * DM + d] = s * (1.f / SEQ);
}
__global__ void proj_k(const float* __restrict__ pooled, const float* __restrict__ pW,
                       const float* __restrict__ pb, float* __restrict__ ptmp) {
  int e0 = blockIdx.x * 64, b = blockIdx.y;
  int el = threadIdx.x & 63, g = threadIdx.x >> 6;
  int e = e0 + el;
  float s = 0.f;
  for (int d = g * 192; d < (g + 1) * 192; ++d)
    s += pooled[b * DM + d] * pW[(size_t)d * EMBED + e];
  __shared__ float red[4][64];
  red[g][el] = s;
  __syncthreads();
  if (g == 0) ptmp[b * EMBED + e] = red[0][el] + red[1][el] + red[2][el] + red[3][el] + pb[e];
}
__global__ void l2_k(const float* __restrict__ ptmp, float* __restrict__ out) {
  int b = blockIdx.x;
  float v[6], ss = 0.f;
#pragma unroll
  for (int i = 0; i < 6; ++i) {
    v[i] = ptmp[(size_t)b * EMBED + threadIdx.x + i * 256];
    ss += v[i] * v[i];
  }
  float tot = block_sum<4>(ss);
  float inv = 1.f / fmaxf(sqrtf(tot), 1e-12f);
#pragma unroll
  for (int i = 0; i < 6; ++i)
    out[(size_t)b * EMBED + threadIdx.x + i * 256] = v[i] * inv;
}

// ---------- launch ----------
extern "C" void kernel_launch(void* const* d_in, const int* in_sizes, int n_in,
                              void* d_out, int out_size, void* d_ws, size_t ws_size,
                              hipStream_t stream) {
  const int*   tok  = (const int*)d_in[0];
  const float* embW = (const float*)d_in[1];
  const float* lnW  = (const float*)d_in[2];
  const float* ipW  = (const float*)d_in[3];
  const float* cW   = (const float*)d_in[4];
  const float* cB   = (const float*)d_in[5];
  const float* dtB  = (const float*)d_in[6];
  const float* Alog = (const float*)d_in[7];
  const float* Dv   = (const float*)d_in[8];
  const float* nW   = (const float*)d_in[9];
  const float* opW  = (const float*)d_in[10];
  const float* fnW  = (const float*)d_in[11];
  const float* pW   = (const float*)d_in[12];
  const float* pb   = (const float*)d_in[13];
  float* out = (float*)d_out;

  char* wsp = (char*)d_ws;
  auto alloc = [&](size_t bytes) {
    char* p = wsp;
    wsp += (bytes + 255) & ~(size_t)255;
    return p;
  };
  float* x      = (float*)alloc((size_t)ROWS * DM * 4);
  float* xbc    = (float*)alloc((size_t)ROWS * CDIM * 4);
  float* dtraw  = (float*)alloc((size_t)ROWS * NH * 4);
  float* pooled = (float*)alloc((size_t)BSZ * DM * 4);
  float* ptmp   = (float*)alloc((size_t)BSZ * EMBED * 4);
  float* fn     = (float*)alloc((size_t)ROWS * DM * 4);
  unsigned short* zb    = (unsigned short*)alloc((size_t)ROWS * DIN * 2);
  unsigned short* xs16  = (unsigned short*)alloc((size_t)ROWS * DIN * 2);
  unsigned short* y16   = (unsigned short*)alloc((size_t)ROWS * DIN * 2);
  unsigned short* h16   = (unsigned short*)alloc((size_t)ROWS * DM * 2);
  unsigned short* yg16  = (unsigned short*)alloc((size_t)ROWS * DIN * 2);
  unsigned short* dtxT  = (unsigned short*)alloc((size_t)BSZ * NH * HP * SEQ * 2);
  unsigned short* Bbf   = (unsigned short*)alloc((size_t)ROWS * NS * 2);
  unsigned short* Cbf   = (unsigned short*)alloc((size_t)ROWS * NS * 2);
  unsigned short* wptA  = (unsigned short*)alloc((size_t)NLAYERS * LDZX * DM * 2);
  unsigned short* wotA  = (unsigned short*)alloc((size_t)NLAYERS * DM * DIN * 2);

  embed_k<<<ROWS, 192, 0, stream>>>(tok, embW, x);
  transpose_cvt<<<dim3(LDZX / 32, DM / 32, NLAYERS), dim3(32, 8), 0, stream>>>(
      ipW, wptA, DM, PROJ_IN, LDZX);
  transpose_cvt<<<dim3(DM / 32, DIN / 32, NLAYERS), dim3(32, 8), 0, stream>>>(
      opW, wotA, DIN, DM, DM);

  for (int l = 0; l < NLAYERS; ++l) {
    rmsnorm_k<unsigned short><<<ROWS, 192, 0, stream>>>(x, lnW + l * DM, h16);
    gemm_k<128, 128, 0><<<dim3(LDZX / 128, ROWS / 128), 256, 0, stream>>>(
        h16, wptA + (size_t)l * LDZX * DM, DM, zb, xbc, dtraw);
    conv_dt_k<<<dim3(7, ROWS / 8), 256, 0, stream>>>(
        xbc, cW + (size_t)l * CDIM * 4, cB + (size_t)l * CDIM, dtraw, dtB + l * NH,
        xs16, dtxT, Bbf, Cbf);
    scan_k<<<dim3(SEQ / 64, NH, BSZ), 256, 0, stream>>>(
        Bbf, Cbf, dtxT, xs16, dtraw, dtB + l * NH, Alog + l * NH, Dv + l * NH, y16);
    gated_rms_k<<<ROWS, 192, 0, stream>>>(y16, zb, nW + (size_t)l * DIN, yg16);
    gemm_k<64, 64, 1><<<dim3(DM / 64, ROWS / 64), 256, 0, stream>>>(
        yg16, wotA + (size_t)l * DM * DIN, DIN, x, x, nullptr);
  }

  rmsnorm_k<float><<<ROWS, 192, 0, stream>>>(x, fnW, fn);
  pool_k<<<dim3(DM / 256, BSZ), 256, 0, stream>>>(fn, pooled);
  proj_k<<<dim3(EMBED / 64, BSZ), 256, 0, stream>>>(pooled, pW, pb, ptmp);
  l2_k<<<BSZ, 256, 0, stream>>>(ptmp, out);
}